// Round 19
// baseline (213.001 us; speedup 1.0000x reference)
//
#include <hip/hip_runtime.h>
#include <cstdint>
#include <cstddef>

typedef __bf16 bf16;
typedef bf16 bf16x8 __attribute__((ext_vector_type(8)));
typedef bf16 bf16x4 __attribute__((ext_vector_type(4)));
typedef float f32x4 __attribute__((ext_vector_type(4)));

typedef __attribute__((address_space(1))) void as1_void;
typedef __attribute__((address_space(3))) void as3_void;

#define INF __builtin_inff()

// ---------------------------------------------------------------------------
// Fused cast fp32->bf16 of all 6 weight/input tensors + zero-pad, one launch.
// wq_b is PRE-SCALED by softmax_scale (rope is linear; scale commutes).
__global__ __launch_bounds__(256) void z100_cast_all(
    const float* __restrict__ x, const float* __restrict__ wq_a,
    const float* __restrict__ wkv_a, const float* __restrict__ wq_b,
    const float* __restrict__ wkv_b, const float* __restrict__ wo,
    bf16* __restrict__ x_bf, bf16* __restrict__ wab_bf,
    bf16* __restrict__ wqb_bf, bf16* __restrict__ wkvb_bf,
    bf16* __restrict__ wo_bf) {
    int i = blockIdx.x * 256 + threadIdx.x;
    const float* s;
    bf16* d;
    float mul = 1.f;
    if (i < 1048576)      { s = x + (size_t)i * 4;                     d = x_bf + (size_t)i * 4; }
    else if (i < 1835008) { int o = i - 1048576; s = wq_a  + (size_t)o * 4; d = wab_bf + (size_t)o * 4; }
    else if (i < 2129920) { int o = i - 1835008; s = wkv_a + (size_t)o * 4; d = wab_bf + 1536ull * 2048 + (size_t)o * 4; }
    else if (i < 3309568) { int o = i - 2129920; s = wq_b  + (size_t)o * 4; d = wqb_bf + (size_t)o * 4;
                            mul = 0.072168783649f; }   // 1/sqrt(192) folded in
    else if (i < 3833856) { int o = i - 3309568; s = wkv_b + (size_t)o * 4; d = wkvb_bf + (size_t)o * 4; }
    else if (i < 4882432) { int o = i - 3833856; s = wo    + (size_t)o * 4; d = wo_bf + (size_t)o * 4; }
    else {                  int o = i - 4882432; bf16x4 z = {};
                            *(bf16x4*)(wab_bf + 2112ull * 2048 + (size_t)o * 4) = z; return; }
    float4 v = *(const float4*)s;
    bf16x4 ovec = { (bf16)(v.x * mul), (bf16)(v.y * mul), (bf16)(v.z * mul), (bf16)(v.w * mul) };
    *(bf16x4*)d = ovec;
}

// ---------------------------------------------------------------------------
// Fused RMSNorm (q + kv in one launch): bid<2048 -> q row, else kv row.
__global__ __launch_bounds__(256) void z100_rmsnorm2(
    const bf16* __restrict__ qa, const float* __restrict__ q_ln,
    const float* __restrict__ kv_ln,
    bf16* __restrict__ qan, bf16* __restrict__ kvc) {
    const int bid = blockIdx.x;
    const bf16* xr;
    const float* w;
    bf16* yr;
    int N; float invN;
    if (bid < 2048) { xr = qa + (size_t)bid * 2112;        w = q_ln;  yr = qan + (size_t)bid * 1536; N = 1536; invN = 1.f / 1536.f; }
    else { int r = bid - 2048; xr = qa + (size_t)r * 2112 + 1536; w = kv_ln; yr = kvc + (size_t)r * 512;  N = 512;  invN = 1.f / 512.f; }
    float ss = 0.f;
    for (int i = threadIdx.x * 8; i < N; i += 2048) {
        bf16x8 v = *(const bf16x8*)(xr + i);
        #pragma unroll
        for (int j = 0; j < 8; ++j) { float f = (float)v[j]; ss += f * f; }
    }
    #pragma unroll
    for (int d = 1; d < 64; d <<= 1) ss += __shfl_xor(ss, d);
    __shared__ float red[4];
    if ((threadIdx.x & 63) == 0) red[threadIdx.x >> 6] = ss;
    __syncthreads();
    float tot = red[0] + red[1] + red[2] + red[3];
    float rs = rsqrtf(tot * invN + 1e-6f);
    for (int i = threadIdx.x * 8; i < N; i += 2048) {
        bf16x8 v = *(const bf16x8*)(xr + i);
        float4 w0 = *(const float4*)(w + i);
        float4 w1 = *(const float4*)(w + i + 4);
        bf16x8 o;
        o[0] = (bf16)((float)v[0] * rs * w0.x); o[1] = (bf16)((float)v[1] * rs * w0.y);
        o[2] = (bf16)((float)v[2] * rs * w0.z); o[3] = (bf16)((float)v[3] * rs * w0.w);
        o[4] = (bf16)((float)v[4] * rs * w1.x); o[5] = (bf16)((float)v[5] * rs * w1.y);
        o[6] = (bf16)((float)v[6] * rs * w1.z); o[7] = (bf16)((float)v[7] * rs * w1.w);
        *(bf16x8*)(yr + i) = o;
    }
}

// ---------------------------------------------------------------------------
// 8-wave GEMM body (R7-measured best): 128x128 tile, BK=32, 512 threads.
// Depth-2 prefetch over 3 LDS buffers, counted s_waitcnt vmcnt(2) + raw
// s_barrier. Templated output type (fp32 or bf16 C-write).
template <typename OutT>
__device__ __forceinline__ void gemm8_body(
    const bf16* __restrict__ A, const bf16* __restrict__ B,
    OutT* __restrict__ C, int N, int K, int ldc, int mblk, int nblk,
    bf16* AsB, bf16* BsB) {
    const int tid = threadIdx.x;
    const int lane = tid & 63, wave = tid >> 6;       // 8 waves
    const int l15 = lane & 15, l4 = lane >> 4;
    const int m0 = mblk * 128, n0 = nblk * 128;
    const int wr = (wave >> 1) * 32, wc = (wave & 1) * 64;

    f32x4 acc[2][4] = {};

    const int srow = lane >> 2;        // 0..15
    const int scol = (lane & 3) * 8;   // 0,8,16,24
    const size_t a_base = (size_t)(m0 + wave * 16 + srow) * K + scol;
    const size_t b_base = (size_t)(n0 + wave * 16 + srow) * K + scol;

    auto stg = [&](int buf, int k0) {
        __builtin_amdgcn_global_load_lds((as1_void*)(void*)(A + a_base + k0),
                                         (as3_void*)(AsB + buf * 4096 + wave * 512), 16, 0, 0);
        __builtin_amdgcn_global_load_lds((as1_void*)(void*)(B + b_base + k0),
                                         (as3_void*)(BsB + buf * 4096 + wave * 512), 16, 0, 0);
    };

    const int nt = K >> 5;
    stg(0, 0);
    stg(1, 32);
    asm volatile("s_waitcnt vmcnt(2)" ::: "memory");
    __builtin_amdgcn_s_barrier();

    int cb = 0, sb = 2;   // compute buffer, stage buffer
    for (int t = 0; t < nt; ++t) {
        if (t + 2 < nt) stg(sb, (t + 2) * 32);
        const bf16* Ab = AsB + cb * 4096;
        const bf16* Bb = BsB + cb * 4096;
        bf16x8 fa[2], fb[4];
        #pragma unroll
        for (int i = 0; i < 2; ++i)
            fa[i] = *(const bf16x8*)(Ab + (wr + 16 * i + l15) * 32 + 8 * l4);
        #pragma unroll
        for (int j = 0; j < 4; ++j)
            fb[j] = *(const bf16x8*)(Bb + (wc + 16 * j + l15) * 32 + 8 * l4);
        #pragma unroll
        for (int i = 0; i < 2; ++i)
            #pragma unroll
            for (int j = 0; j < 4; ++j)
                acc[i][j] = __builtin_amdgcn_mfma_f32_16x16x32_bf16(fa[i], fb[j], acc[i][j], 0, 0, 0);
        if (t + 2 < nt) { asm volatile("s_waitcnt vmcnt(2)" ::: "memory"); }
        else            { asm volatile("s_waitcnt vmcnt(0)" ::: "memory"); }
        __builtin_amdgcn_s_barrier();
        cb = (cb == 2) ? 0 : cb + 1;
        sb = (sb == 2) ? 0 : sb + 1;
    }

    #pragma unroll
    for (int i = 0; i < 2; ++i) {
        int row0 = m0 + wr + 16 * i + 4 * l4;
        #pragma unroll
        for (int j = 0; j < 4; ++j) {
            int col = n0 + wc + 16 * j + l15;
            if (col < N) {
                #pragma unroll
                for (int jj = 0; jj < 4; ++jj)
                    C[(size_t)(row0 + jj) * ldc + col] = (OutT)acc[i][j][jj];
            }
        }
    }
}

// generic fp32-out: grid (nblk, mblk) — NO XCD swizzle (R13 lesson)
__global__ __launch_bounds__(512) void z100_gemm8(
    const bf16* __restrict__ A, const bf16* __restrict__ B,
    float* __restrict__ C, int N, int K, int ldc) {
    __shared__ alignas(16) bf16 As[3 * 128 * 32];
    __shared__ alignas(16) bf16 Bs[3 * 128 * 32];
    gemm8_body<float>(A, B, C, N, K, ldc, blockIdx.y, blockIdx.x, As, Bs);
}

// bf16-out: grid (nblk, mblk)
__global__ __launch_bounds__(512) void z100_gemm8_bf(
    const bf16* __restrict__ A, const bf16* __restrict__ B,
    bf16* __restrict__ C, int N, int K, int ldc) {
    __shared__ alignas(16) bf16 As[3 * 128 * 32];
    __shared__ alignas(16) bf16 Bs[3 * 128 * 32];
    gemm8_body<bf16>(A, B, C, N, K, ldc, blockIdx.y, blockIdx.x, As, Bs);
}

// fused QB + KVB GEMMs, PACKED to 640 blocks (all resident at 3 blocks/CU):
// bid<384 -> one QB tile (48 K-steps); else one KVB tile PAIR (2 x 16 K-steps).
// Removes the 896-on-768-slots straggler wave + length raggedness (R18 lever).
__global__ __launch_bounds__(512) void z100_gemm_qkv(
    const bf16* __restrict__ qan, const bf16* __restrict__ wqb, bf16* __restrict__ qf,
    const bf16* __restrict__ kvc, const bf16* __restrict__ wkvb, bf16* __restrict__ kvbf) {
    __shared__ alignas(16) bf16 As[3 * 128 * 32];
    __shared__ alignas(16) bf16 Bs[3 * 128 * 32];
    const int bid = blockIdx.x;
    if (bid < 384) {
        gemm8_body<bf16>(qan, wqb, qf, 3072, 1536, 3072, bid / 24, bid % 24, As, Bs);
    } else {
        int b = bid - 384;                 // 0..255 -> KVB tiles b and b+256
        gemm8_body<bf16>(kvc, wkvb, kvbf, 4096, 512, 4096, b >> 5, b & 31, As, Bs);
        int b2 = b + 256;
        gemm8_body<bf16>(kvc, wkvb, kvbf, 4096, 512, 4096, b2 >> 5, b2 & 31, As, Bs);
    }
}

// ---------------------------------------------------------------------------
// Fused prep: bid<512 -> V-transpose tile; else pe rope (q_pe + k_pe).
__global__ __launch_bounds__(256) void z100_prep(
    const bf16* __restrict__ kvb, const bf16* __restrict__ q_f,
    const bf16* __restrict__ qa,
    const float* __restrict__ fc, const float* __restrict__ fs,
    bf16* __restrict__ vt, bf16* __restrict__ qpe, bf16* __restrict__ kpe) {
    const int bid = blockIdx.x;
    const int tid = threadIdx.x;
    if (bid < 512) {
        const int st = bid & 31, h = bid >> 5;
        const int s0 = st * 64;
        __shared__ alignas(16) bf16 tile[64 * 132];
        #pragma unroll
        for (int i = 0; i < 4; ++i) {
            int slot = i * 256 + tid;
            int r = slot >> 4, c8 = slot & 15;
            bf16x8 v = *(const bf16x8*)(kvb + (size_t)(s0 + r) * 4096 + h * 256 + 128 + c8 * 8);
            *(bf16x8*)(tile + r * 132 + c8 * 8) = v;
        }
        __syncthreads();
        #pragma unroll
        for (int i = 0; i < 4; ++i) {
            int slot = i * 256 + tid;
            int d = slot >> 3, ch = slot & 7;
            bf16x8 o;
            #pragma unroll
            for (int j = 0; j < 8; ++j) o[j] = tile[(ch * 8 + j) * 132 + d];
            *(bf16x8*)(vt + ((size_t)h * 128 + d) * 2048 + s0 + ch * 8) = o;
        }
        return;
    }
    const int QTOT = 2048 * 16 * 32;
    int u = (bid - 512) * 256 + tid;
    if (u < QTOT) {
        int i = u & 31;
        int h = (u >> 5) & 15;
        int s = u >> 9;
        float c = fc[s * 32 + i], sn = fs[s * 32 + i];
        float x1 = (float)q_f[(size_t)s * 3072 + h * 192 + 128 + 2 * i];
        float x2 = (float)q_f[(size_t)s * 3072 + h * 192 + 128 + 2 * i + 1];
        qpe[(size_t)s * 1024 + h * 64 + 2 * i]     = (bf16)(x1 * c - x2 * sn);
        qpe[(size_t)s * 1024 + h * 64 + 2 * i + 1] = (bf16)(x1 * sn + x2 * c);
    } else {
        int v = u - QTOT;
        int i = v & 31;
        int s = v >> 5;
        float c = fc[s * 32 + i], sn = fs[s * 32 + i];
        float x1 = (float)qa[(size_t)s * 2112 + 2048 + 2 * i];
        float x2 = (float)qa[(size_t)s * 2112 + 2048 + 2 * i + 1];
        kpe[(size_t)s * 64 + 2 * i]     = (bf16)(x1 * c - x2 * sn);
        kpe[(size_t)s * 64 + 2 * i + 1] = (bf16)(x1 * sn + x2 * c);
    }
}

// ---------------------------------------------------------------------------
// Static work-packing table: 32 block-slots per head covering the 40 (qt,chk)
// chunks. Small chunks (2/4/6-tile diagonals + tails) pair into 10-tile slots;
// full 8-tile chunks stay single. Grid = 512 = exactly 2 blocks/CU residency.
// code = qt*4 + chk; -1 = no second item.
__device__ const signed char z100_item0[32] = {
    0*4+0, 1*4+0, 4*4+1, 5*4+1, 8*4+2, 9*4+2, 12*4+3, 13*4+3,
    5*4+0, 6*4+0, 7*4+0, 7*4+1, 8*4+1, 9*4+0, 9*4+1, 10*4+0,
    10*4+1, 11*4+0, 11*4+1, 11*4+2, 12*4+1, 12*4+2, 13*4+0, 13*4+1,
    13*4+2, 14*4+0, 14*4+1, 14*4+2, 15*4+0, 15*4+1, 15*4+2, 15*4+3 };
__device__ const signed char z100_item1[32] = {
    3*4+0, 2*4+0, 4*4+0, 6*4+1, 8*4+0, 10*4+2, 12*4+0, 14*4+3,
    -1, -1, -1, -1, -1, -1, -1, -1,
    -1, -1, -1, -1, -1, -1, -1, -1,
    -1, -1, -1, -1, -1, -1, -1, -1 };

// Flash attention (R17 math, statically packed 512-block grid): 8 waves x
// 128 q-rows, KVBLK=64, dbuf async LDS, T13 defer-max, direct staging.
// Each block runs 1-2 work items sequentially (state reset between items);
// per-tile math, flush paths, and slot numbering identical to R17.
__global__ __launch_bounds__(512) void z100_attn(
    const bf16* __restrict__ q_f, const bf16* __restrict__ qpe,
    const bf16* __restrict__ kvb, const bf16* __restrict__ kpe,
    const bf16* __restrict__ v_t, bf16* __restrict__ opart, float* __restrict__ ml,
    bf16* __restrict__ ao) {
    const int bid = blockIdx.x;
    const int wk = (bid & 7) * 64 + (bid >> 3);   // bijective: 512 % 8 == 0
    const int h = wk >> 5;
    const int s = wk & 31;

    const int tid = threadIdx.x;
    const int lane = tid & 63, wave = tid >> 6;
    const int l15 = lane & 15, l4 = lane >> 4;

    __shared__ alignas(16) bf16 Ks[2][64 * 192];
    __shared__ alignas(16) bf16 Vs[2][128 * 64];

    const bf16* Vh = v_t + (size_t)h * 128 * 2048;

    // K staging sources (per-lane, item-invariant): LDS dest LINEAR; row perm
    // + XOR swizzle on the source channel. chx<16 -> kvb nope; else shared kpe.
    const bf16* kp0[3];
    int kstep[3];
    #pragma unroll
    for (int i = 0; i < 3; ++i) {
        int off = (wave * 3 + i) * 1024 + lane * 16;
        int r = off / 384;
        int ch = (off % 384) >> 4;
        int ksrc = (r & 0x23) | ((r & 0x0C) << 1) | ((r & 0x10) >> 2);
        int chx = ch ^ (r & 7);   // XOR stays within nope/pe halves (mask<8)
        if (chx < 16) { kp0[i] = kvb + (size_t)ksrc * 4096 + h * 256 + chx * 8; kstep[i] = 4096; }
        else          { kp0[i] = kpe + (size_t)ksrc * 64 + (chx - 16) * 8;      kstep[i] = 64; }
    }
    int voff[2];
    #pragma unroll
    for (int i = 0; i < 2; ++i) {
        int off = (wave * 2 + i) * 1024 + lane * 16;
        int d = off >> 7;
        int ch = (off >> 4) & 7;
        voff[i] = d * 2048 + (ch ^ (d & 7)) * 8;
    }

    auto stage = [&](int buf, int k0) {
        #pragma unroll
        for (int i = 0; i < 3; ++i)
            __builtin_amdgcn_global_load_lds(
                (as1_void*)(void*)(kp0[i] + (size_t)k0 * kstep[i]),
                (as3_void*)((char*)&Ks[buf][0] + (wave * 3 + i) * 1024), 16, 0, 0);
        #pragma unroll
        for (int i = 0; i < 2; ++i)
            __builtin_amdgcn_global_load_lds(
                (as1_void*)(void*)(Vh + k0 + voff[i]),
                (as3_void*)((char*)&Vs[buf][0] + (wave * 2 + i) * 1024), 16, 0, 0);
    };

    const int c0 = z100_item0[s], c1 = z100_item1[s];

    #pragma unroll 1
    for (int it = 0; it < 2; ++it) {
        const int code = it ? c1 : c0;
        if (code < 0) break;
        const int qt = code >> 2, chk = code & 3;
        const int q0 = qt * 128;
        const int kstart = chk * 512;
        const int kend = min(q0 + 128, kstart + 512);
        const int nt = (kend - kstart) >> 6;
        const int g = qt >> 2, rr = qt & 3;
        const int slot = h * 40 + 2 * g * (g + 1) + rr * (g + 1) + chk;
        const bool single = (qt < 4);   // np==1: whole causal range here
        const int wrow_max = q0 + wave * 16 + 15;
        const int diag_k0 = q0 + (wave >> 2) * 64;

        // Q fragments for this item: nope (c=0..3) from q_f; pe from qpe.
        bf16x8 qf[6];
        {
            const int qrow = q0 + wave * 16 + l15;
            const bf16* qn = q_f + (size_t)qrow * 3072 + h * 192 + 8 * l4;
            #pragma unroll
            for (int c = 0; c < 4; ++c) qf[c] = *(const bf16x8*)(qn + 32 * c);
            const bf16* qp = qpe + (size_t)qrow * 1024 + h * 64 + 8 * l4;
            qf[4] = *(const bf16x8*)(qp);
            qf[5] = *(const bf16x8*)(qp + 32);
        }

        f32x4 oacc[8] = {};
        float m_r = -INF, l_r = 0.f;

        stage(0, kstart);
        __syncthreads();
        int cur = 0;
        for (int t = 0; t < nt; ++t) {
            const int k0 = kstart + t * 64;
            if (t + 1 < nt) stage(cur ^ 1, k0 + 64);   // prefetch overlaps compute

            if (k0 <= wrow_max) {   // skip tiles entirely above this wave's rows
                const char* KsC = (const char*)&Ks[cur][0];
                const char* VsC = (const char*)&Vs[cur][0];

                // QK^T swapped: mfma(K, Q) -> D[key][q]; lane holds 16 scores.
                f32x4 sc[4];
                __builtin_amdgcn_s_setprio(1);
                #pragma unroll
                for (int kt = 0; kt < 4; ++kt) {
                    f32x4 a = { 0.f, 0.f, 0.f, 0.f };
                    int r = 16 * kt + l15;
                    #pragma unroll
                    for (int c = 0; c < 6; ++c) {
                        int byteo = (r * 384 + c * 64 + l4 * 16) ^ ((r & 7) << 4);
                        bf16x8 kf = *(const bf16x8*)(KsC + byteo);
                        a = __builtin_amdgcn_mfma_f32_16x16x32_bf16(kf, qf[c], a, 0, 0, 0);
                    }
                    sc[kt] = a;
                }
                __builtin_amdgcn_s_setprio(0);

                if (k0 == diag_k0) {   // causal mask at this wave's diagonal tile
                    int qrow = (wave & 3) * 16 + l15;   // row - k0
                    #pragma unroll
                    for (int kt = 0; kt < 4; ++kt)
                        #pragma unroll
                        for (int r = 0; r < 4; ++r) {
                            int kl = ((kt >> 1) << 5) | (l4 << 3) | ((kt & 1) << 2) | r;
                            if (kl > qrow) sc[kt][r] = -INF;
                        }
                }

                // online softmax with T13 defer-max (threshold 8)
                float mx = -INF;
                #pragma unroll
                for (int kt = 0; kt < 4; ++kt)
                    #pragma unroll
                    for (int r = 0; r < 4; ++r) mx = fmaxf(mx, sc[kt][r]);
                mx = fmaxf(mx, __shfl_xor(mx, 16));
                mx = fmaxf(mx, __shfl_xor(mx, 32));
                if (!__all(mx <= m_r + 8.f)) {
                    float mnew = fmaxf(m_r, mx);
                    float corr = __expf(m_r - mnew);   // m_r=-inf -> corr=0
                    float c_r[4];
                    #pragma unroll
                    for (int r = 0; r < 4; ++r) c_r[r] = __shfl(corr, 20 * l4 + r);
                    #pragma unroll
                    for (int dt = 0; dt < 8; ++dt)
                        #pragma unroll
                        for (int r = 0; r < 4; ++r) oacc[dt][r] *= c_r[r];
                    l_r *= corr;
                    m_r = mnew;
                }
                float rs = 0.f;
                #pragma unroll
                for (int kt = 0; kt < 4; ++kt)
                    #pragma unroll
                    for (int r = 0; r < 4; ++r) {
                        float pv = __expf(sc[kt][r] - m_r);
                        sc[kt][r] = pv;
                        rs += pv;
                    }
                rs += __shfl_xor(rs, 16);
                rs += __shfl_xor(rs, 32);
                l_r += rs;

                // P -> A-fragments: pure in-lane relabeling (K staging perm)
                bf16x8 pf[2];
                #pragma unroll
                for (int c2 = 0; c2 < 2; ++c2)
                    #pragma unroll
                    for (int i = 0; i < 8; ++i)
                        pf[c2][i] = (bf16)sc[2 * c2 + (i >> 2)][i & 3];

                __builtin_amdgcn_s_setprio(1);
                #pragma unroll
                for (int dt = 0; dt < 8; ++dt) {
                    #pragma unroll
                    for (int c2 = 0; c2 < 2; ++c2) {
                        int d = 16 * dt + l15;
                        int byteo = (d * 128 + c2 * 64 + l4 * 16) ^ ((d & 7) << 4);
                        bf16x8 vf = *(const bf16x8*)(VsC + byteo);
                        oacc[dt] = __builtin_amdgcn_mfma_f32_16x16x32_bf16(pf[c2], vf, oacc[dt], 0, 0, 0);
                    }
                }
                __builtin_amdgcn_s_setprio(0);
            }

            __syncthreads();   // drains prefetch vmcnt; all waves done with cur
            cur ^= 1;
        }

        const int qr_base = wave * 16;
        if (single) {
            // np==1: normalize in-register and write final output directly.
            float inv_l = 1.f / l_r;   // l_r > 0: every row has >= 1 causal key
            float il_r[4];
            #pragma unroll
            for (int r = 0; r < 4; ++r) il_r[r] = __shfl(inv_l, 20 * l4 + r);
            #pragma unroll
            for (int dt = 0; dt < 8; ++dt) {
                int d = 16 * dt + l15;
                #pragma unroll
                for (int r = 0; r < 4; ++r) {
                    int qg = q0 + qr_base + 4 * l4 + r;
                    ao[(size_t)qg * 2048 + h * 128 + d] = (bf16)(oacc[dt][r] * il_r[r]);
                }
            }
        } else {
            // multi-chunk: write partial 128x128 + m/l at compact slot
            if (lane < 16) {
                ml[(size_t)slot * 256 + qr_base + lane] = m_r;
                ml[(size_t)slot * 256 + 128 + qr_base + lane] = l_r;
            }
            bf16* ob = opart + (size_t)slot * 16384;
            #pragma unroll
            for (int dt = 0; dt < 8; ++dt) {
                int d = 16 * dt + l15;
                #pragma unroll
                for (int r = 0; r < 4; ++r) {
                    int qr = qr_base + 4 * l4 + r;
                    ob[qr * 128 + d] = (bf16)oacc[dt][r];
                }
            }
        }
    }
}

// combine 2..4 partials -> ao bf16 [S][H*128]; qt = blockIdx.x + 4 (qt>=4 only;
// qt 0..3 were written directly by the attn kernel). FULLY LINEAR reads.
__global__ __launch_bounds__(512) void z100_attn_combine(
    const bf16* __restrict__ opart, const float* __restrict__ ml, bf16* __restrict__ ao) {
    const int qt = blockIdx.x + 4, h = blockIdx.y;
    const int t = threadIdx.x;
    const int np = (qt >> 2) + 1;
    int base = 0;
    for (int j = 0; j < qt; ++j) base += (j >> 2) + 1;
    const int slot0 = h * 40 + base;
    #pragma unroll 1
    for (int it = 0; it < 4; ++it) {
        const int c = it * 512 + t;     // 16B chunk id within [128][128]
        const int qr = c >> 4;          // row
        const int dc = (c & 15) * 8;    // col start (elements)
        float m[4], l[4], w[4];
        float M = -INF;
        #pragma unroll
        for (int i = 0; i < 4; ++i)
            if (i < np) {
                m[i] = ml[(size_t)(slot0 + i) * 256 + qr];
                l[i] = ml[(size_t)(slot0 + i) * 256 + 128 + qr];
                M = fmaxf(M, m[i]);
            }
        float L = 0.f;
        #pragma unroll
        for (int i = 0; i < 4; ++i)
            if (i < np) {
                w[i] = __expf(m[i] - M);   // m=-inf (row uncovered) -> w=0
                L += w[i] * l[i];
            }
        float invL = 1.f / L;
        float acc[8] = {};
        #pragma unroll
        for (int i = 0; i < 4; ++i)
            if (i < np) {
                bf16x8 a = *(const bf16x8*)(opart + (size_t)(slot0 + i) * 16384 + (size_t)c * 8);
                #pragma unroll
                for (int j = 0; j < 8; ++j) acc[j] += w[i] * (float)a[j];
            }
        bf16x8 o;
        #pragma unroll
        for (int j = 0; j < 8; ++j) o[j] = (bf16)(acc[j] * invL);
        *(bf16x8*)(ao + (size_t)(qt * 128 + qr) * 2048 + h * 128 + dc) = o;
    }
}

// ---------------------------------------------------------------------------
extern "C" void kernel_launch(void* const* d_in, const int* in_sizes, int n_in,
                              void* d_out, int out_size, void* d_ws, size_t ws_size,
                              hipStream_t stream) {
    (void)in_sizes; (void)n_in; (void)out_size; (void)ws_size;
    const float* x     = (const float*)d_in[0];
    const float* fc    = (const float*)d_in[1];
    const float* fs    = (const float*)d_in[2];
    const float* wq_a  = (const float*)d_in[3];
    const float* q_ln  = (const float*)d_in[4];
    const float* wq_b  = (const float*)d_in[5];
    const float* wkv_a = (const float*)d_in[6];
    const float* kv_ln = (const float*)d_in[7];
    const float* wkv_b = (const float*)d_in[8];
    const float* wo    = (const float*)d_in[9];
    float* out = (float*)d_out;

    char* p = (char*)d_ws;
    auto alloc = [&](size_t bytes) {
        char* r = p;
        p += (bytes + 255) & ~(size_t)255;
        return r;
    };
    // phase-1 buffers (dead before attention) — opart/ml alias this region
    char* phase1  = p;
    bf16* x_bf    = (bf16*)alloc(2048ull * 2048 * 2);
    bf16* wab_bf  = (bf16*)alloc(2176ull * 2048 * 2);  // wq_a(1536)+wkv_a(576)+pad(64)
    bf16* qa_bf   = (bf16*)alloc(2048ull * 2112 * 2);  // [q 1536 | kv_c 512 | k_pe 64] bf16
    bf16* qan_bf  = (bf16*)alloc(2048ull * 1536 * 2);
    // live buffers
    bf16* wqb_bf  = (bf16*)alloc(3072ull * 1536 * 2);
    bf16* wkvb_bf = (bf16*)alloc(4096ull * 512 * 2);
    bf16* wo_bf   = (bf16*)alloc(2048ull * 2048 * 2);
    bf16* q_f     = (bf16*)alloc(2048ull * 3072 * 2);   // bf16 GEMM output (scaled)
    bf16* kvc_bf  = (bf16*)alloc(2048ull * 512 * 2);
    bf16* kvb_f   = (bf16*)alloc(2048ull * 4096 * 2);   // bf16 GEMM output
    bf16* qpe     = (bf16*)alloc(2048ull * 16 * 64 * 2);
    bf16* kpe     = (bf16*)alloc(2048ull * 64 * 2);
    bf16* v_t     = (bf16*)alloc(16ull * 128 * 2048 * 2);
    bf16* ao_bf   = (bf16*)alloc(2048ull * 2048 * 2);
    // aliased over phase-1 region (~29.9 MB; opart 20.0 + ml 0.66 MB)
    bf16* opart   = (bf16*)phase1;                     // [640 slots][128*128]
    float* mlbuf  = (float*)(phase1 + 640ull * 16384 * 2);

    // fused casts (6 tensors + pad-zero; wq_b pre-scaled), one launch
    z100_cast_all<<<19200, 256, 0, stream>>>(x, wq_a, wkv_a, wq_b, wkv_b, wo,
                                             x_bf, wab_bf, wqb_bf, wkvb_bf, wo_bf);

    // merged A-GEMM: [q_a | kv_a] (8-wave, depth-2, bf16 out)
    z100_gemm8_bf<<<dim3(17, 16), 512, 0, stream>>>(x_bf, wab_bf, qa_bf, 2112, 2048, 2112);
    // fused RMSNorm (q rows 0..2047, kv rows 2048..4095)
    z100_rmsnorm2<<<4096, 256, 0, stream>>>(qa_bf, q_ln, kv_ln, qan_bf, kvc_bf);

    // fused QB + KVB GEMMs, packed to 640 blocks (all resident)
    z100_gemm_qkv<<<dim3(640), 512, 0, stream>>>(qan_bf, wqb_bf, q_f, kvc_bf, wkvb_bf, kvb_f);

    // fused prep: V transpose (512 blocks) + pe rope (4352 blocks)
    z100_prep<<<4864, 256, 0, stream>>>(kvb_f, q_f, qa_bf, fc, fs, v_t, qpe, kpe);

    // attention: 512 statically-packed blocks (exact residency) + combine
    z100_attn<<<dim3(512), 512, 0, stream>>>(q_f, qpe, kvb_f, kpe, v_t, opart, mlbuf, ao_bf);
    z100_attn_combine<<<dim3(12, 16), 512, 0, stream>>>(opart, mlbuf, ao_bf);

    // output projection (8-wave, depth-2, fp32 straight to d_out)
    z100_gemm8<<<dim3(16, 16), 512, 0, stream>>>(ao_bf, wo_bf, out, 2048, 2048, 2048);
}

// Round 20
// 211.444 us; speedup vs baseline: 1.0074x; 1.0074x over previous
//
#include <hip/hip_runtime.h>
#include <cstdint>
#include <cstddef>

typedef __bf16 bf16;
typedef bf16 bf16x8 __attribute__((ext_vector_type(8)));
typedef bf16 bf16x4 __attribute__((ext_vector_type(4)));
typedef float f32x4 __attribute__((ext_vector_type(4)));

typedef __attribute__((address_space(1))) void as1_void;
typedef __attribute__((address_space(3))) void as3_void;

#define INF __builtin_inff()

// ---------------------------------------------------------------------------
// Fused cast fp32->bf16 of all 6 weight/input tensors + zero-pad, one launch.
// wq_b is PRE-SCALED by softmax_scale (rope is linear; scale commutes).
__global__ __launch_bounds__(256) void z100_cast_all(
    const float* __restrict__ x, const float* __restrict__ wq_a,
    const float* __restrict__ wkv_a, const float* __restrict__ wq_b,
    const float* __restrict__ wkv_b, const float* __restrict__ wo,
    bf16* __restrict__ x_bf, bf16* __restrict__ wab_bf,
    bf16* __restrict__ wqb_bf, bf16* __restrict__ wkvb_bf,
    bf16* __restrict__ wo_bf) {
    int i = blockIdx.x * 256 + threadIdx.x;
    const float* s;
    bf16* d;
    float mul = 1.f;
    if (i < 1048576)      { s = x + (size_t)i * 4;                     d = x_bf + (size_t)i * 4; }
    else if (i < 1835008) { int o = i - 1048576; s = wq_a  + (size_t)o * 4; d = wab_bf + (size_t)o * 4; }
    else if (i < 2129920) { int o = i - 1835008; s = wkv_a + (size_t)o * 4; d = wab_bf + 1536ull * 2048 + (size_t)o * 4; }
    else if (i < 3309568) { int o = i - 2129920; s = wq_b  + (size_t)o * 4; d = wqb_bf + (size_t)o * 4;
                            mul = 0.072168783649f; }   // 1/sqrt(192) folded in
    else if (i < 3833856) { int o = i - 3309568; s = wkv_b + (size_t)o * 4; d = wkvb_bf + (size_t)o * 4; }
    else if (i < 4882432) { int o = i - 3833856; s = wo    + (size_t)o * 4; d = wo_bf + (size_t)o * 4; }
    else {                  int o = i - 4882432; bf16x4 z = {};
                            *(bf16x4*)(wab_bf + 2112ull * 2048 + (size_t)o * 4) = z; return; }
    float4 v = *(const float4*)s;
    bf16x4 ovec = { (bf16)(v.x * mul), (bf16)(v.y * mul), (bf16)(v.z * mul), (bf16)(v.w * mul) };
    *(bf16x4*)d = ovec;
}

// ---------------------------------------------------------------------------
// Fused RMSNorm (q + kv in one launch): bid<2048 -> q row, else kv row.
__global__ __launch_bounds__(256) void z100_rmsnorm2(
    const bf16* __restrict__ qa, const float* __restrict__ q_ln,
    const float* __restrict__ kv_ln,
    bf16* __restrict__ qan, bf16* __restrict__ kvc) {
    const int bid = blockIdx.x;
    const bf16* xr;
    const float* w;
    bf16* yr;
    int N; float invN;
    if (bid < 2048) { xr = qa + (size_t)bid * 2112;        w = q_ln;  yr = qan + (size_t)bid * 1536; N = 1536; invN = 1.f / 1536.f; }
    else { int r = bid - 2048; xr = qa + (size_t)r * 2112 + 1536; w = kv_ln; yr = kvc + (size_t)r * 512;  N = 512;  invN = 1.f / 512.f; }
    float ss = 0.f;
    for (int i = threadIdx.x * 8; i < N; i += 2048) {
        bf16x8 v = *(const bf16x8*)(xr + i);
        #pragma unroll
        for (int j = 0; j < 8; ++j) { float f = (float)v[j]; ss += f * f; }
    }
    #pragma unroll
    for (int d = 1; d < 64; d <<= 1) ss += __shfl_xor(ss, d);
    __shared__ float red[4];
    if ((threadIdx.x & 63) == 0) red[threadIdx.x >> 6] = ss;
    __syncthreads();
    float tot = red[0] + red[1] + red[2] + red[3];
    float rs = rsqrtf(tot * invN + 1e-6f);
    for (int i = threadIdx.x * 8; i < N; i += 2048) {
        bf16x8 v = *(const bf16x8*)(xr + i);
        float4 w0 = *(const float4*)(w + i);
        float4 w1 = *(const float4*)(w + i + 4);
        bf16x8 o;
        o[0] = (bf16)((float)v[0] * rs * w0.x); o[1] = (bf16)((float)v[1] * rs * w0.y);
        o[2] = (bf16)((float)v[2] * rs * w0.z); o[3] = (bf16)((float)v[3] * rs * w0.w);
        o[4] = (bf16)((float)v[4] * rs * w1.x); o[5] = (bf16)((float)v[5] * rs * w1.y);
        o[6] = (bf16)((float)v[6] * rs * w1.z); o[7] = (bf16)((float)v[7] * rs * w1.w);
        *(bf16x8*)(yr + i) = o;
    }
}

// ---------------------------------------------------------------------------
// 8-wave GEMM body (R7-measured best): 128x128 tile, BK=32, 512 threads.
// Depth-2 prefetch over 3 LDS buffers, counted s_waitcnt vmcnt(2) + raw
// s_barrier. Templated output type (fp32 or bf16 C-write).
template <typename OutT>
__device__ __forceinline__ void gemm8_body(
    const bf16* __restrict__ A, const bf16* __restrict__ B,
    OutT* __restrict__ C, int N, int K, int ldc, int mblk, int nblk,
    bf16* AsB, bf16* BsB) {
    const int tid = threadIdx.x;
    const int lane = tid & 63, wave = tid >> 6;       // 8 waves
    const int l15 = lane & 15, l4 = lane >> 4;
    const int m0 = mblk * 128, n0 = nblk * 128;
    const int wr = (wave >> 1) * 32, wc = (wave & 1) * 64;

    f32x4 acc[2][4] = {};

    const int srow = lane >> 2;        // 0..15
    const int scol = (lane & 3) * 8;   // 0,8,16,24
    const size_t a_base = (size_t)(m0 + wave * 16 + srow) * K + scol;
    const size_t b_base = (size_t)(n0 + wave * 16 + srow) * K + scol;

    auto stg = [&](int buf, int k0) {
        __builtin_amdgcn_global_load_lds((as1_void*)(void*)(A + a_base + k0),
                                         (as3_void*)(AsB + buf * 4096 + wave * 512), 16, 0, 0);
        __builtin_amdgcn_global_load_lds((as1_void*)(void*)(B + b_base + k0),
                                         (as3_void*)(BsB + buf * 4096 + wave * 512), 16, 0, 0);
    };

    const int nt = K >> 5;
    stg(0, 0);
    stg(1, 32);
    asm volatile("s_waitcnt vmcnt(2)" ::: "memory");
    __builtin_amdgcn_s_barrier();

    int cb = 0, sb = 2;   // compute buffer, stage buffer
    for (int t = 0; t < nt; ++t) {
        if (t + 2 < nt) stg(sb, (t + 2) * 32);
        const bf16* Ab = AsB + cb * 4096;
        const bf16* Bb = BsB + cb * 4096;
        bf16x8 fa[2], fb[4];
        #pragma unroll
        for (int i = 0; i < 2; ++i)
            fa[i] = *(const bf16x8*)(Ab + (wr + 16 * i + l15) * 32 + 8 * l4);
        #pragma unroll
        for (int j = 0; j < 4; ++j)
            fb[j] = *(const bf16x8*)(Bb + (wc + 16 * j + l15) * 32 + 8 * l4);
        #pragma unroll
        for (int i = 0; i < 2; ++i)
            #pragma unroll
            for (int j = 0; j < 4; ++j)
                acc[i][j] = __builtin_amdgcn_mfma_f32_16x16x32_bf16(fa[i], fb[j], acc[i][j], 0, 0, 0);
        if (t + 2 < nt) { asm volatile("s_waitcnt vmcnt(2)" ::: "memory"); }
        else            { asm volatile("s_waitcnt vmcnt(0)" ::: "memory"); }
        __builtin_amdgcn_s_barrier();
        cb = (cb == 2) ? 0 : cb + 1;
        sb = (sb == 2) ? 0 : sb + 1;
    }

    #pragma unroll
    for (int i = 0; i < 2; ++i) {
        int row0 = m0 + wr + 16 * i + 4 * l4;
        #pragma unroll
        for (int j = 0; j < 4; ++j) {
            int col = n0 + wc + 16 * j + l15;
            if (col < N) {
                #pragma unroll
                for (int jj = 0; jj < 4; ++jj)
                    C[(size_t)(row0 + jj) * ldc + col] = (OutT)acc[i][j][jj];
            }
        }
    }
}

// generic fp32-out: grid (nblk, mblk) — NO XCD swizzle (R13 lesson)
__global__ __launch_bounds__(512) void z100_gemm8(
    const bf16* __restrict__ A, const bf16* __restrict__ B,
    float* __restrict__ C, int N, int K, int ldc) {
    __shared__ alignas(16) bf16 As[3 * 128 * 32];
    __shared__ alignas(16) bf16 Bs[3 * 128 * 32];
    gemm8_body<float>(A, B, C, N, K, ldc, blockIdx.y, blockIdx.x, As, Bs);
}

// bf16-out: grid (nblk, mblk)
__global__ __launch_bounds__(512) void z100_gemm8_bf(
    const bf16* __restrict__ A, const bf16* __restrict__ B,
    bf16* __restrict__ C, int N, int K, int ldc) {
    __shared__ alignas(16) bf16 As[3 * 128 * 32];
    __shared__ alignas(16) bf16 Bs[3 * 128 * 32];
    gemm8_body<bf16>(A, B, C, N, K, ldc, blockIdx.y, blockIdx.x, As, Bs);
}

// fused QB (384 blocks) + KVB (512 blocks), bf16 outputs, default dispatch
// (R19 lesson: pair-packing the short KVB tiles was neutral-negative —
// the HW scheduler back-fills short overflow blocks fine; keep 896 blocks)
__global__ __launch_bounds__(512) void z100_gemm_qkv(
    const bf16* __restrict__ qan, const bf16* __restrict__ wqb, bf16* __restrict__ qf,
    const bf16* __restrict__ kvc, const bf16* __restrict__ wkvb, bf16* __restrict__ kvbf) {
    __shared__ alignas(16) bf16 As[3 * 128 * 32];
    __shared__ alignas(16) bf16 Bs[3 * 128 * 32];
    const int bid = blockIdx.x;
    if (bid < 384) gemm8_body<bf16>(qan, wqb, qf, 3072, 1536, 3072, bid / 24, bid % 24, As, Bs);
    else { int b = bid - 384; gemm8_body<bf16>(kvc, wkvb, kvbf, 4096, 512, 4096, b / 32, b % 32, As, Bs); }
}

// ---------------------------------------------------------------------------
// Fused prep: bid<512 -> V-transpose tile; else pe rope (q_pe + k_pe).
__global__ __launch_bounds__(256) void z100_prep(
    const bf16* __restrict__ kvb, const bf16* __restrict__ q_f,
    const bf16* __restrict__ qa,
    const float* __restrict__ fc, const float* __restrict__ fs,
    bf16* __restrict__ vt, bf16* __restrict__ qpe, bf16* __restrict__ kpe) {
    const int bid = blockIdx.x;
    const int tid = threadIdx.x;
    if (bid < 512) {
        const int st = bid & 31, h = bid >> 5;
        const int s0 = st * 64;
        __shared__ alignas(16) bf16 tile[64 * 132];
        #pragma unroll
        for (int i = 0; i < 4; ++i) {
            int slot = i * 256 + tid;
            int r = slot >> 4, c8 = slot & 15;
            bf16x8 v = *(const bf16x8*)(kvb + (size_t)(s0 + r) * 4096 + h * 256 + 128 + c8 * 8);
            *(bf16x8*)(tile + r * 132 + c8 * 8) = v;
        }
        __syncthreads();
        #pragma unroll
        for (int i = 0; i < 4; ++i) {
            int slot = i * 256 + tid;
            int d = slot >> 3, ch = slot & 7;
            bf16x8 o;
            #pragma unroll
            for (int j = 0; j < 8; ++j) o[j] = tile[(ch * 8 + j) * 132 + d];
            *(bf16x8*)(vt + ((size_t)h * 128 + d) * 2048 + s0 + ch * 8) = o;
        }
        return;
    }
    const int QTOT = 2048 * 16 * 32;
    int u = (bid - 512) * 256 + tid;
    if (u < QTOT) {
        int i = u & 31;
        int h = (u >> 5) & 15;
        int s = u >> 9;
        float c = fc[s * 32 + i], sn = fs[s * 32 + i];
        float x1 = (float)q_f[(size_t)s * 3072 + h * 192 + 128 + 2 * i];
        float x2 = (float)q_f[(size_t)s * 3072 + h * 192 + 128 + 2 * i + 1];
        qpe[(size_t)s * 1024 + h * 64 + 2 * i]     = (bf16)(x1 * c - x2 * sn);
        qpe[(size_t)s * 1024 + h * 64 + 2 * i + 1] = (bf16)(x1 * sn + x2 * c);
    } else {
        int v = u - QTOT;
        int i = v & 31;
        int s = v >> 5;
        float c = fc[s * 32 + i], sn = fs[s * 32 + i];
        float x1 = (float)qa[(size_t)s * 2112 + 2048 + 2 * i];
        float x2 = (float)qa[(size_t)s * 2112 + 2048 + 2 * i + 1];
        kpe[(size_t)s * 64 + 2 * i]     = (bf16)(x1 * c - x2 * sn);
        kpe[(size_t)s * 64 + 2 * i + 1] = (bf16)(x1 * sn + x2 * c);
    }
}

// ---------------------------------------------------------------------------
// Static work-packing table: 32 block-slots per head covering the 40 (qt,chk)
// chunks. Small chunks (2/4/6-tile diagonals + tails) pair into 10-tile slots;
// full 8-tile chunks stay single. Grid = 512 = exactly 2 blocks/CU residency.
// code = qt*4 + chk; -1 = no second item.
__device__ const signed char z100_item0[32] = {
    0*4+0, 1*4+0, 4*4+1, 5*4+1, 8*4+2, 9*4+2, 12*4+3, 13*4+3,
    5*4+0, 6*4+0, 7*4+0, 7*4+1, 8*4+1, 9*4+0, 9*4+1, 10*4+0,
    10*4+1, 11*4+0, 11*4+1, 11*4+2, 12*4+1, 12*4+2, 13*4+0, 13*4+1,
    13*4+2, 14*4+0, 14*4+1, 14*4+2, 15*4+0, 15*4+1, 15*4+2, 15*4+3 };
__device__ const signed char z100_item1[32] = {
    3*4+0, 2*4+0, 4*4+0, 6*4+1, 8*4+0, 10*4+2, 12*4+0, 14*4+3,
    -1, -1, -1, -1, -1, -1, -1, -1,
    -1, -1, -1, -1, -1, -1, -1, -1,
    -1, -1, -1, -1, -1, -1, -1, -1 };

// Flash attention (R17 math, statically packed 512-block grid): 8 waves x
// 128 q-rows, KVBLK=64, dbuf async LDS, T13 defer-max, direct staging.
// Each block runs 1-2 work items sequentially (state reset between items);
// per-tile math, flush paths, and slot numbering identical to R17.
__global__ __launch_bounds__(512) void z100_attn(
    const bf16* __restrict__ q_f, const bf16* __restrict__ qpe,
    const bf16* __restrict__ kvb, const bf16* __restrict__ kpe,
    const bf16* __restrict__ v_t, bf16* __restrict__ opart, float* __restrict__ ml,
    bf16* __restrict__ ao) {
    const int bid = blockIdx.x;
    const int wk = (bid & 7) * 64 + (bid >> 3);   // bijective: 512 % 8 == 0
    const int h = wk >> 5;
    const int s = wk & 31;

    const int tid = threadIdx.x;
    const int lane = tid & 63, wave = tid >> 6;
    const int l15 = lane & 15, l4 = lane >> 4;

    __shared__ alignas(16) bf16 Ks[2][64 * 192];
    __shared__ alignas(16) bf16 Vs[2][128 * 64];

    const bf16* Vh = v_t + (size_t)h * 128 * 2048;

    // K staging sources (per-lane, item-invariant): LDS dest LINEAR; row perm
    // + XOR swizzle on the source channel. chx<16 -> kvb nope; else shared kpe.
    const bf16* kp0[3];
    int kstep[3];
    #pragma unroll
    for (int i = 0; i < 3; ++i) {
        int off = (wave * 3 + i) * 1024 + lane * 16;
        int r = off / 384;
        int ch = (off % 384) >> 4;
        int ksrc = (r & 0x23) | ((r & 0x0C) << 1) | ((r & 0x10) >> 2);
        int chx = ch ^ (r & 7);   // XOR stays within nope/pe halves (mask<8)
        if (chx < 16) { kp0[i] = kvb + (size_t)ksrc * 4096 + h * 256 + chx * 8; kstep[i] = 4096; }
        else          { kp0[i] = kpe + (size_t)ksrc * 64 + (chx - 16) * 8;      kstep[i] = 64; }
    }
    int voff[2];
    #pragma unroll
    for (int i = 0; i < 2; ++i) {
        int off = (wave * 2 + i) * 1024 + lane * 16;
        int d = off >> 7;
        int ch = (off >> 4) & 7;
        voff[i] = d * 2048 + (ch ^ (d & 7)) * 8;
    }

    auto stage = [&](int buf, int k0) {
        #pragma unroll
        for (int i = 0; i < 3; ++i)
            __builtin_amdgcn_global_load_lds(
                (as1_void*)(void*)(kp0[i] + (size_t)k0 * kstep[i]),
                (as3_void*)((char*)&Ks[buf][0] + (wave * 3 + i) * 1024), 16, 0, 0);
        #pragma unroll
        for (int i = 0; i < 2; ++i)
            __builtin_amdgcn_global_load_lds(
                (as1_void*)(void*)(Vh + k0 + voff[i]),
                (as3_void*)((char*)&Vs[buf][0] + (wave * 2 + i) * 1024), 16, 0, 0);
    };

    const int c0 = z100_item0[s], c1 = z100_item1[s];

    #pragma unroll 1
    for (int it = 0; it < 2; ++it) {
        const int code = it ? c1 : c0;
        if (code < 0) break;
        const int qt = code >> 2, chk = code & 3;
        const int q0 = qt * 128;
        const int kstart = chk * 512;
        const int kend = min(q0 + 128, kstart + 512);
        const int nt = (kend - kstart) >> 6;
        const int g = qt >> 2, rr = qt & 3;
        const int slot = h * 40 + 2 * g * (g + 1) + rr * (g + 1) + chk;
        const bool single = (qt < 4);   // np==1: whole causal range here
        const int wrow_max = q0 + wave * 16 + 15;
        const int diag_k0 = q0 + (wave >> 2) * 64;

        // Q fragments for this item: nope (c=0..3) from q_f; pe from qpe.
        bf16x8 qf[6];
        {
            const int qrow = q0 + wave * 16 + l15;
            const bf16* qn = q_f + (size_t)qrow * 3072 + h * 192 + 8 * l4;
            #pragma unroll
            for (int c = 0; c < 4; ++c) qf[c] = *(const bf16x8*)(qn + 32 * c);
            const bf16* qp = qpe + (size_t)qrow * 1024 + h * 64 + 8 * l4;
            qf[4] = *(const bf16x8*)(qp);
            qf[5] = *(const bf16x8*)(qp + 32);
        }

        f32x4 oacc[8] = {};
        float m_r = -INF, l_r = 0.f;

        stage(0, kstart);
        __syncthreads();
        int cur = 0;
        for (int t = 0; t < nt; ++t) {
            const int k0 = kstart + t * 64;
            if (t + 1 < nt) stage(cur ^ 1, k0 + 64);   // prefetch overlaps compute

            if (k0 <= wrow_max) {   // skip tiles entirely above this wave's rows
                const char* KsC = (const char*)&Ks[cur][0];
                const char* VsC = (const char*)&Vs[cur][0];

                // QK^T swapped: mfma(K, Q) -> D[key][q]; lane holds 16 scores.
                f32x4 sc[4];
                __builtin_amdgcn_s_setprio(1);
                #pragma unroll
                for (int kt = 0; kt < 4; ++kt) {
                    f32x4 a = { 0.f, 0.f, 0.f, 0.f };
                    int r = 16 * kt + l15;
                    #pragma unroll
                    for (int c = 0; c < 6; ++c) {
                        int byteo = (r * 384 + c * 64 + l4 * 16) ^ ((r & 7) << 4);
                        bf16x8 kf = *(const bf16x8*)(KsC + byteo);
                        a = __builtin_amdgcn_mfma_f32_16x16x32_bf16(kf, qf[c], a, 0, 0, 0);
                    }
                    sc[kt] = a;
                }
                __builtin_amdgcn_s_setprio(0);

                if (k0 == diag_k0) {   // causal mask at this wave's diagonal tile
                    int qrow = (wave & 3) * 16 + l15;   // row - k0
                    #pragma unroll
                    for (int kt = 0; kt < 4; ++kt)
                        #pragma unroll
                        for (int r = 0; r < 4; ++r) {
                            int kl = ((kt >> 1) << 5) | (l4 << 3) | ((kt & 1) << 2) | r;
                            if (kl > qrow) sc[kt][r] = -INF;
                        }
                }

                // online softmax with T13 defer-max (threshold 8)
                float mx = -INF;
                #pragma unroll
                for (int kt = 0; kt < 4; ++kt)
                    #pragma unroll
                    for (int r = 0; r < 4; ++r) mx = fmaxf(mx, sc[kt][r]);
                mx = fmaxf(mx, __shfl_xor(mx, 16));
                mx = fmaxf(mx, __shfl_xor(mx, 32));
                if (!__all(mx <= m_r + 8.f)) {
                    float mnew = fmaxf(m_r, mx);
                    float corr = __expf(m_r - mnew);   // m_r=-inf -> corr=0
                    float c_r[4];
                    #pragma unroll
                    for (int r = 0; r < 4; ++r) c_r[r] = __shfl(corr, 20 * l4 + r);
                    #pragma unroll
                    for (int dt = 0; dt < 8; ++dt)
                        #pragma unroll
                        for (int r = 0; r < 4; ++r) oacc[dt][r] *= c_r[r];
                    l_r *= corr;
                    m_r = mnew;
                }
                float rs = 0.f;
                #pragma unroll
                for (int kt = 0; kt < 4; ++kt)
                    #pragma unroll
                    for (int r = 0; r < 4; ++r) {
                        float pv = __expf(sc[kt][r] - m_r);
                        sc[kt][r] = pv;
                        rs += pv;
                    }
                rs += __shfl_xor(rs, 16);
                rs += __shfl_xor(rs, 32);
                l_r += rs;

                // P -> A-fragments: pure in-lane relabeling (K staging perm)
                bf16x8 pf[2];
                #pragma unroll
                for (int c2 = 0; c2 < 2; ++c2)
                    #pragma unroll
                    for (int i = 0; i < 8; ++i)
                        pf[c2][i] = (bf16)sc[2 * c2 + (i >> 2)][i & 3];

                __builtin_amdgcn_s_setprio(1);
                #pragma unroll
                for (int dt = 0; dt < 8; ++dt) {
                    #pragma unroll
                    for (int c2 = 0; c2 < 2; ++c2) {
                        int d = 16 * dt + l15;
                        int byteo = (d * 128 + c2 * 64 + l4 * 16) ^ ((d & 7) << 4);
                        bf16x8 vf = *(const bf16x8*)(VsC + byteo);
                        oacc[dt] = __builtin_amdgcn_mfma_f32_16x16x32_bf16(pf[c2], vf, oacc[dt], 0, 0, 0);
                    }
                }
                __builtin_amdgcn_s_setprio(0);
            }

            __syncthreads();   // drains prefetch vmcnt; all waves done with cur
            cur ^= 1;
        }

        const int qr_base = wave * 16;
        if (single) {
            // np==1: normalize in-register and write final output directly.
            float inv_l = 1.f / l_r;   // l_r > 0: every row has >= 1 causal key
            float il_r[4];
            #pragma unroll
            for (int r = 0; r < 4; ++r) il_r[r] = __shfl(inv_l, 20 * l4 + r);
            #pragma unroll
            for (int dt = 0; dt < 8; ++dt) {
                int d = 16 * dt + l15;
                #pragma unroll
                for (int r = 0; r < 4; ++r) {
                    int qg = q0 + qr_base + 4 * l4 + r;
                    ao[(size_t)qg * 2048 + h * 128 + d] = (bf16)(oacc[dt][r] * il_r[r]);
                }
            }
        } else {
            // multi-chunk: write partial 128x128 + m/l at compact slot
            if (lane < 16) {
                ml[(size_t)slot * 256 + qr_base + lane] = m_r;
                ml[(size_t)slot * 256 + 128 + qr_base + lane] = l_r;
            }
            bf16* ob = opart + (size_t)slot * 16384;
            #pragma unroll
            for (int dt = 0; dt < 8; ++dt) {
                int d = 16 * dt + l15;
                #pragma unroll
                for (int r = 0; r < 4; ++r) {
                    int qr = qr_base + 4 * l4 + r;
                    ob[qr * 128 + d] = (bf16)oacc[dt][r];
                }
            }
        }
    }
}

// combine 2..4 partials -> ao bf16 [S][H*128]; qt = blockIdx.x + 4 (qt>=4 only;
// qt 0..3 were written directly by the attn kernel). FULLY LINEAR reads.
__global__ __launch_bounds__(512) void z100_attn_combine(
    const bf16* __restrict__ opart, const float* __restrict__ ml, bf16* __restrict__ ao) {
    const int qt = blockIdx.x + 4, h = blockIdx.y;
    const int t = threadIdx.x;
    const int np = (qt >> 2) + 1;
    int base = 0;
    for (int j = 0; j < qt; ++j) base += (j >> 2) + 1;
    const int slot0 = h * 40 + base;
    #pragma unroll 1
    for (int it = 0; it < 4; ++it) {
        const int c = it * 512 + t;     // 16B chunk id within [128][128]
        const int qr = c >> 4;          // row
        const int dc = (c & 15) * 8;    // col start (elements)
        float m[4], l[4], w[4];
        float M = -INF;
        #pragma unroll
        for (int i = 0; i < 4; ++i)
            if (i < np) {
                m[i] = ml[(size_t)(slot0 + i) * 256 + qr];
                l[i] = ml[(size_t)(slot0 + i) * 256 + 128 + qr];
                M = fmaxf(M, m[i]);
            }
        float L = 0.f;
        #pragma unroll
        for (int i = 0; i < 4; ++i)
            if (i < np) {
                w[i] = __expf(m[i] - M);   // m=-inf (row uncovered) -> w=0
                L += w[i] * l[i];
            }
        float invL = 1.f / L;
        float acc[8] = {};
        #pragma unroll
        for (int i = 0; i < 4; ++i)
            if (i < np) {
                bf16x8 a = *(const bf16x8*)(opart + (size_t)(slot0 + i) * 16384 + (size_t)c * 8);
                #pragma unroll
                for (int j = 0; j < 8; ++j) acc[j] += w[i] * (float)a[j];
            }
        bf16x8 o;
        #pragma unroll
        for (int j = 0; j < 8; ++j) o[j] = (bf16)(acc[j] * invL);
        *(bf16x8*)(ao + (size_t)(qt * 128 + qr) * 2048 + h * 128 + dc) = o;
    }
}

// ---------------------------------------------------------------------------
extern "C" void kernel_launch(void* const* d_in, const int* in_sizes, int n_in,
                              void* d_out, int out_size, void* d_ws, size_t ws_size,
                              hipStream_t stream) {
    (void)in_sizes; (void)n_in; (void)out_size; (void)ws_size;
    const float* x     = (const float*)d_in[0];
    const float* fc    = (const float*)d_in[1];
    const float* fs    = (const float*)d_in[2];
    const float* wq_a  = (const float*)d_in[3];
    const float* q_ln  = (const float*)d_in[4];
    const float* wq_b  = (const float*)d_in[5];
    const float* wkv_a = (const float*)d_in[6];
    const float* kv_ln = (const float*)d_in[7];
    const float* wkv_b = (const float*)d_in[8];
    const float* wo    = (const float*)d_in[9];
    float* out = (float*)d_out;

    char* p = (char*)d_ws;
    auto alloc = [&](size_t bytes) {
        char* r = p;
        p += (bytes + 255) & ~(size_t)255;
        return r;
    };
    // phase-1 buffers (dead before attention) — opart/ml alias this region
    char* phase1  = p;
    bf16* x_bf    = (bf16*)alloc(2048ull * 2048 * 2);
    bf16* wab_bf  = (bf16*)alloc(2176ull * 2048 * 2);  // wq_a(1536)+wkv_a(576)+pad(64)
    bf16* qa_bf   = (bf16*)alloc(2048ull * 2112 * 2);  // [q 1536 | kv_c 512 | k_pe 64] bf16
    bf16* qan_bf  = (bf16*)alloc(2048ull * 1536 * 2);
    // live buffers
    bf16* wqb_bf  = (bf16*)alloc(3072ull * 1536 * 2);
    bf16* wkvb_bf = (bf16*)alloc(4096ull * 512 * 2);
    bf16* wo_bf   = (bf16*)alloc(2048ull * 2048 * 2);
    bf16* q_f     = (bf16*)alloc(2048ull * 3072 * 2);   // bf16 GEMM output (scaled)
    bf16* kvc_bf  = (bf16*)alloc(2048ull * 512 * 2);
    bf16* kvb_f   = (bf16*)alloc(2048ull * 4096 * 2);   // bf16 GEMM output
    bf16* qpe     = (bf16*)alloc(2048ull * 16 * 64 * 2);
    bf16* kpe     = (bf16*)alloc(2048ull * 64 * 2);
    bf16* v_t     = (bf16*)alloc(16ull * 128 * 2048 * 2);
    bf16* ao_bf   = (bf16*)alloc(2048ull * 2048 * 2);
    // aliased over phase-1 region (~29.9 MB; opart 20.0 + ml 0.66 MB)
    bf16* opart   = (bf16*)phase1;                     // [640 slots][128*128]
    float* mlbuf  = (float*)(phase1 + 640ull * 16384 * 2);

    // fused casts (6 tensors + pad-zero; wq_b pre-scaled), one launch
    z100_cast_all<<<19200, 256, 0, stream>>>(x, wq_a, wkv_a, wq_b, wkv_b, wo,
                                             x_bf, wab_bf, wqb_bf, wkvb_bf, wo_bf);

    // merged A-GEMM: [q_a | kv_a] (8-wave, depth-2, bf16 out)
    z100_gemm8_bf<<<dim3(17, 16), 512, 0, stream>>>(x_bf, wab_bf, qa_bf, 2112, 2048, 2112);
    // fused RMSNorm (q rows 0..2047, kv rows 2048..4095)
    z100_rmsnorm2<<<4096, 256, 0, stream>>>(qa_bf, q_ln, kv_ln, qan_bf, kvc_bf);

    // fused QB + KVB GEMMs (896 blocks, 8-wave, bf16 out, default dispatch)
    z100_gemm_qkv<<<dim3(896), 512, 0, stream>>>(qan_bf, wqb_bf, q_f, kvc_bf, wkvb_bf, kvb_f);

    // fused prep: V transpose (512 blocks) + pe rope (4352 blocks)
    z100_prep<<<4864, 256, 0, stream>>>(kvb_f, q_f, qa_bf, fc, fs, v_t, qpe, kpe);

    // attention: 512 statically-packed blocks (exact residency) + combine
    z100_attn<<<dim3(512), 512, 0, stream>>>(q_f, qpe, kvb_f, kpe, v_t, opart, mlbuf, ao_bf);
    z100_attn_combine<<<dim3(12, 16), 512, 0, stream>>>(opart, mlbuf, ao_bf);

    // output projection (8-wave, depth-2, fp32 straight to d_out)
    z100_gemm8<<<dim3(16, 16), 512, 0, stream>>>(ao_bf, wo_bf, out, 2048, 2048, 2048);
}